// Round 18
// baseline (23.825 us; speedup 1.0000x reference)
//
#include <hip/hip_runtime.h>
#include <math.h>

// Problem constants (from setup_inputs)
#define NG    1000   // num_graphs
#define NPG   128    // nodes_per_graph
#define FF    59     // features
#define D1    128    // hidden 1
#define D2    256    // hidden 2
#define EPSV  1e-5f

// NOTE on the neighbor graph: the reference's  d2 + eye(n)*inf  makes every
// OFF-diagonal entry 0*inf = NaN (diag = +inf); top_k(-d2) then selects,
// stably, the 3 lowest indices != i:
//   idx[i] = {0,1,2} for i>=3;  {1,2,3}, {0,2,3}, {0,1,3} for i=0,1,2.
// So v_j = x_j @ w1b is only needed for j in {0,1,2,3}, and
//   sum_edges relu(u_i + v_j) = sum_i S3(i) + sum_{i<3} [relu(u_i+v3) - relu(u_i+v_i)]
// where S3(i) = relu(u_i+v0)+relu(u_i+v1)+relu(u_i+v2),
//       u_i = x_i @ (w1a - w1b) + b1   (b1 folded into wu's k=59 row, x pad=1.0)
//
// Round-18: R17 (best, 23.43) + head w2 diet done RIGHT: bf16 pair-packed
// w2q[c2][d] (uint2 = bf16 rows 4c2..4c2+3 at col d) keeps the f-major
// coalesced orientation (512 B/wave contiguous), halves head L2 bytes
// (131->65 KB/block, the largest per-block L2 term) and cuts load issues
// 128->32. R16's failure was the per-thread-ROW layout (64 lines/wave) +
// strided builder gather — both fixed here. Builder is row-coalesced.

typedef short  short8  __attribute__((ext_vector_type(8)));
typedef float  f32x4   __attribute__((ext_vector_type(4)));

#define WS_WB_SHORTS  8192    // wb blob at short offset 8192 (byte 16384)
#define WS_W2Q_SHORTS 16384   // w2q at short offset 16384 (byte 32768), 64 KB

static __device__ __forceinline__ unsigned short f2bf(float f) {
    union { float f; unsigned u; } v; v.f = f;
    unsigned r = v.u + 0x7FFFu + ((v.u >> 16) & 1u);   // RNE
    return (unsigned short)(r >> 16);
}
static __device__ __forceinline__ float ubits2f(unsigned u) {
    union { unsigned u; float f; } v; v.u = u; return v.f;
}

// Build one row's two k-step A-fragments from the LDS x-image.
// k=59 -> 1.0 (bias row; wb blob has 0 there so vv is unaffected), k>59 -> 0.
static __device__ __forceinline__ void frags_from_lds(
    const float* __restrict__ xs, int row, int lg, short8* a)
{
    const float* r = xs + row * FF;
    float xv[8];
    #pragma unroll
    for (int j = 0; j < 8; ++j) xv[j] = r[lg * 8 + j];
    #pragma unroll
    for (int j = 0; j < 8; ++j) a[0][j] = (short)f2bf(xv[j]);
    if (lg < 3) {
        #pragma unroll
        for (int j = 0; j < 8; ++j) xv[j] = r[32 + lg * 8 + j];
    } else {
        xv[0] = r[56]; xv[1] = r[57]; xv[2] = r[58]; xv[3] = 1.0f;
        #pragma unroll
        for (int j = 4; j < 8; ++j) xv[j] = 0.0f;
    }
    #pragma unroll
    for (int j = 0; j < 8; ++j) a[1][j] = (short)f2bf(xv[j]);
}

// ---------------------------------------------------------------------------
// Kernel B (48 wgs x 64 thr):
//  wgs 0..15  : wu fragments (w1a-w1b, bias row k=59)
//  wgs 16..31 : wb fragments (w1b, zero at k=59)
//  wgs 32..47 : w2q packed bf16 pairs (row-coalesced reads, coalesced writes)
// ---------------------------------------------------------------------------
__global__ __launch_bounds__(64) void ecn_blob(
    const float* __restrict__ w1, const float* __restrict__ b1,
    const float* __restrict__ w2, short* __restrict__ blob)
{
    const int bid = blockIdx.x;
    const int l = threadIdx.x;
    if (bid < 32) {
        const bool isB = (bid >= 16);
        const int fid = isB ? (bid - 16) : bid;
        const int s = fid >> 3, nt = fid & 7;
        const int lr = l & 15, lg = l >> 4;
        const int d = nt * 16 + lr, k0 = s * 32 + lg * 8;
        short8 pk;
        #pragma unroll
        for (int j = 0; j < 8; ++j) {
            int k = k0 + j;
            float v = 0.0f;
            if (k < FF) {
                float wb_ = w1[(size_t)(FF + k) * D1 + d];
                v = isB ? wb_ : (w1[(size_t)k * D1 + d] - wb_);
            } else if (k == FF && !isB) {
                v = b1[d];                   // bias row only in wu
            }
            pk[j] = (short)f2bf(v);
        }
        *(short8*)&blob[(size_t)(isB ? WS_WB_SHORTS : 0) + ((s * 8 + nt) * 64 + l) * 8] = pk;
    } else {
        // w2q: uint2 at (c2, d) = {pack(f=4c2, 4c2+1), pack(4c2+2, 4c2+3)} at col d.
        // Reads row-coalesced (w2[f][d], 64 lanes contiguous), writes coalesced.
        uint2* w2q = (uint2*)(blob + WS_W2Q_SHORTS);
        const int b = bid - 32;              // 0..15 -> c2 = 2b, 2b+1
        #pragma unroll
        for (int cc = 0; cc < 2; ++cc) {
            int c2 = b * 2 + cc;
            #pragma unroll
            for (int dc = 0; dc < 4; ++dc) {
                int d = dc * 64 + l;
                unsigned px = ((unsigned)f2bf(w2[(size_t)(4 * c2 + 1) * D2 + d]) << 16)
                            |  (unsigned)f2bf(w2[(size_t)(4 * c2 + 0) * D2 + d]);
                unsigned py = ((unsigned)f2bf(w2[(size_t)(4 * c2 + 3) * D2 + d]) << 16)
                            |  (unsigned)f2bf(w2[(size_t)(4 * c2 + 2) * D2 + d]);
                w2q[(size_t)c2 * D2 + d] = make_uint2(px, py);
            }
        }
    }
}

// ---------------------------------------------------------------------------
// Kernel F: per-graph fused. global_load_lds x-staging + distributed vv +
// per-nt streaming u-GEMM + epilogue + BN1 + packed-bf16 head MLP + sigmoid.
// ---------------------------------------------------------------------------
__global__ __launch_bounds__(256, 4) void ecn_fused(
    const float* __restrict__ x, const short* __restrict__ blob,
    const float* __restrict__ g1, const float* __restrict__ be1,
    const float* __restrict__ m1, const float* __restrict__ v1,
    const float* __restrict__ b2,
    const float* __restrict__ g2, const float* __restrict__ be2,
    const float* __restrict__ m2, const float* __restrict__ v2,
    const float* __restrict__ w3, const float* __restrict__ b3,
    const float* __restrict__ g3, const float* __restrict__ be3,
    const float* __restrict__ m3, const float* __restrict__ v3,
    float* __restrict__ out)
{
    // XCD-aware bijective swizzle: 1000 = 8 * 125
    const int bid = blockIdx.x;
    const int g = (bid & 7) * 125 + (bid >> 3);
    const int t = threadIdx.x;

    __shared__ __align__(16) float xs[NPG * FF];   // 30208 B, linear f32 image
    __shared__ float vvsh[4 * D1];   // 2 KB
    __shared__ float Sp[4][D1];      // 2 KB
    __shared__ float x2s[D1];        // 512 B
    __shared__ float rpart[4];
    // total ~35 KB -> 4 blocks/CU

    // ---- stage x: 1888 float4 chunks via global_load_lds (direct-to-LDS) ----
    {
        const float4* xg4 = (const float4*)(x + (size_t)g * NPG * FF);
        float4* xs4 = (float4*)xs;
        #pragma unroll
        for (int k = 0; k < 8; ++k) {
            int e = t + k * 256;
            if (k < 7 || e < 1888)
                __builtin_amdgcn_global_load_lds(&xg4[e], &xs4[e], 16, 0, 0);
        }
    }
    __syncthreads();   // drains vmcnt (incl. global_load_lds) + barrier

    const int wave = t >> 6, l = t & 63;
    const int lr = l & 15, lg = l >> 4;
    const int i0 = wave * 32 + lr;        // mt=0 row
    const int i1 = i0 + 16;               // mt=1 row

    const short8* wu8 = (const short8*)blob;
    const short8* wb8 = (const short8*)(blob + WS_WB_SHORTS);

    // ---- A fragments from LDS: rows i0, i1 (u-GEMM) and row lr (vv tile) ----
    short8 a0[2], a1[2], av[2];
    frags_from_lds(xs, i0, lg, a0);
    frags_from_lds(xs, i1, lg, a1);
    if (wave == 0) { av[0] = a0[0]; av[1] = a0[1]; }   // wave 0: lr == i0
    else           frags_from_lds(xs, lr, lg, av);

    // ---- vv: this wave computes nt-tiles {2*wave, 2*wave+1} of x_{0..15}@w1b ----
    #pragma unroll
    for (int p = 0; p < 2; ++p) {
        const int nt = wave * 2 + p;
        f32x4 cv = (f32x4)0.0f;
        cv = __builtin_amdgcn_mfma_f32_16x16x32_bf16(av[0], wb8[nt * 64 + l],       cv, 0, 0, 0);
        cv = __builtin_amdgcn_mfma_f32_16x16x32_bf16(av[1], wb8[(8 + nt) * 64 + l], cv, 0, 0, 0);
        if (lg == 0) {                    // rows 0..3 = lanes 0..15, q=0..3
            #pragma unroll
            for (int q = 0; q < 4; ++q) vvsh[q * D1 + nt * 16 + lr] = cv[q];
        }
    }
    __syncthreads();                      // vvsh complete

    // ---- per-nt streaming u-GEMM + fused relu-edge aggregation ----
    #pragma unroll
    for (int nt = 0; nt < 8; ++nt) {
        short8 b0 = wu8[nt * 64 + l];
        short8 b1f = wu8[(8 + nt) * 64 + l];
        f32x4 c0 = (f32x4)0.0f, c1 = (f32x4)0.0f;
        c0 = __builtin_amdgcn_mfma_f32_16x16x32_bf16(a0[0], b0,  c0, 0, 0, 0);
        c0 = __builtin_amdgcn_mfma_f32_16x16x32_bf16(a0[1], b1f, c0, 0, 0, 0);
        c1 = __builtin_amdgcn_mfma_f32_16x16x32_bf16(a1[0], b0,  c1, 0, 0, 0);
        c1 = __builtin_amdgcn_mfma_f32_16x16x32_bf16(a1[1], b1f, c1, 0, 0, 0);

        const int d = nt * 16 + lr;
        const float v0 = vvsh[d], v1_ = vvsh[128 + d], v2_ = vvsh[256 + d], v3_ = vvsh[384 + d];
        float s = 0.0f;
        #pragma unroll
        for (int q = 0; q < 4; ++q) {
            float u = c0[q];              // b1 already inside via k=59 row
            s += fmaxf(u + v0, 0.0f) + fmaxf(u + v1_, 0.0f) + fmaxf(u + v2_, 0.0f);
            u = c1[q];
            s += fmaxf(u + v0, 0.0f) + fmaxf(u + v1_, 0.0f) + fmaxf(u + v2_, 0.0f);
        }
        if (wave == 0 && lg == 0) {       // global rows 0,1,2 = c0 q=0..2
            float u0 = c0[0], u1 = c0[1], u2 = c0[2];
            s += fmaxf(u0 + v3_, 0.0f) - fmaxf(u0 + v0,  0.0f);
            s += fmaxf(u1 + v3_, 0.0f) - fmaxf(u1 + v1_, 0.0f);
            s += fmaxf(u2 + v3_, 0.0f) - fmaxf(u2 + v2_, 0.0f);
        }
        s += __shfl_xor(s, 16);
        s += __shfl_xor(s, 32);
        if (lg == 0) Sp[wave][d] = s;
    }
    __syncthreads();

    // ---- BN1 (affine commutes with the means) -> x2 in LDS ----
    if (t < D1) {
        float tot = Sp[0][t] + Sp[1][t] + Sp[2][t] + Sp[3][t];
        float sc = g1[t] * rsqrtf(v1[t] + EPSV);
        x2s[t] = sc * (tot * (1.0f / (3 * NPG))) + (be1[t] - m1[t] * sc);
    }
    __syncthreads();

    // ---- head MLP + sigmoid: packed-bf16 w2q, 32 coalesced uint2 loads ----
    {
        const uint2* w2q = (const uint2*)(blob + WS_W2Q_SHORTS);
        float h0 = b2[t], h1 = 0.0f, h2 = 0.0f, h3 = 0.0f;
        #pragma unroll 8
        for (int c2 = 0; c2 < 32; ++c2) {
            uint2 w = w2q[(size_t)c2 * D2 + t];
            const int f = c2 * 4;
            h0 = fmaf(x2s[f + 0], ubits2f(w.x << 16),          h0);
            h1 = fmaf(x2s[f + 1], ubits2f(w.x & 0xffff0000u),  h1);
            h2 = fmaf(x2s[f + 2], ubits2f(w.y << 16),          h2);
            h3 = fmaf(x2s[f + 3], ubits2f(w.y & 0xffff0000u),  h3);
        }
        float h = (h0 + h1) + (h2 + h3);
        h = fmaxf(h, 0.0f);
        float sc2 = g2[t] * rsqrtf(v2[t] + EPSV);
        h = sc2 * h + (be2[t] - m2[t] * sc2);
        float r = h * w3[t];
        #pragma unroll
        for (int off = 32; off > 0; off >>= 1) r += __shfl_down(r, off);
        if ((t & 63) == 0) rpart[t >> 6] = r;
    }
    __syncthreads();
    if (t == 0) {
        float s = rpart[0] + rpart[1] + rpart[2] + rpart[3] + b3[0];
        s = fmaxf(s, 0.0f);
        float sc3 = g3[0] * rsqrtf(v3[0] + EPSV);
        s = sc3 * s + (be3[0] - m3[0] * sc3);
        out[g] = 1.0f / (1.0f + expf(-s));
    }
}

extern "C" void kernel_launch(void* const* d_in, const int* in_sizes, int n_in,
                              void* d_out, int out_size, void* d_ws, size_t ws_size,
                              hipStream_t stream) {
    const float* x   = (const float*)d_in[0];
    // d_in[1] = pos — unused: the reference's knn degenerates (see NOTE)
    const float* w1  = (const float*)d_in[2];
    const float* b1  = (const float*)d_in[3];
    const float* g1  = (const float*)d_in[4];
    const float* be1 = (const float*)d_in[5];
    const float* m1  = (const float*)d_in[6];
    const float* v1  = (const float*)d_in[7];
    const float* w2  = (const float*)d_in[8];
    const float* b2  = (const float*)d_in[9];
    const float* g2  = (const float*)d_in[10];
    const float* be2 = (const float*)d_in[11];
    const float* m2  = (const float*)d_in[12];
    const float* v2  = (const float*)d_in[13];
    const float* w3  = (const float*)d_in[14];
    const float* b3  = (const float*)d_in[15];
    const float* g3  = (const float*)d_in[16];
    const float* be3 = (const float*)d_in[17];
    const float* m3  = (const float*)d_in[18];
    const float* v3  = (const float*)d_in[19];
    float* outp = (float*)d_out;

    short* blob = (short*)d_ws;

    ecn_blob<<<48, 64, 0, stream>>>(w1, b1, w2, blob);
    ecn_fused<<<NG, 256, 0, stream>>>(x, blob, g1, be1, m1, v1,
                                      b2, g2, be2, m2, v2,
                                      w3, b3, g3, be3, m3, v3, outp);
}

// Round 19
// 23.677 us; speedup vs baseline: 1.0062x; 1.0062x over previous
//
#include <hip/hip_runtime.h>
#include <math.h>

// Problem constants (from setup_inputs)
#define NG    1000   // num_graphs
#define NPG   128    // nodes_per_graph
#define FF    59     // features
#define D1    128    // hidden 1
#define D2    256    // hidden 2
#define EPSV  1e-5f

// NOTE on the neighbor graph: the reference's  d2 + eye(n)*inf  makes every
// OFF-diagonal entry 0*inf = NaN (diag = +inf); top_k(-d2) then selects,
// stably, the 3 lowest indices != i:
//   idx[i] = {0,1,2} for i>=3;  {1,2,3}, {0,2,3}, {0,1,3} for i=0,1,2.
// So v_j = x_j @ w1b is only needed for j in {0,1,2,3}, and
//   sum_edges relu(u_i + v_j) = sum_i S3(i) + sum_{i<3} [relu(u_i+v3) - relu(u_i+v_i)]
// where S3(i) = relu(u_i+v0)+relu(u_i+v1)+relu(u_i+v2),
//       u_i = x_i @ (w1a - w1b) + b1   (b1 folded into wu's k=59 row, x pad=1.0)
//
// Round-19: R17 (best, 23.43) minus the block-wide phase-lock: each wave
// stages ITS OWN 32-row x-section (global_load_lds, per-wave uniform base),
// drains with a per-wave s_waitcnt vmcnt(0) (no barrier), loads av rows 0-15
// direct from global (2 loads, concurrent with staging), and computes its own
// FULL vv (16 wb-MFMA) distributed via __shfl (R8's verified epilogue) — no
// vvsh, no vv barrier. Barriers 5 -> 3; waves run decoupled through ~90% of
// the kernel. Head reverted to R17 fp32 w2 (R18 w2q was neutral).

typedef short  short8  __attribute__((ext_vector_type(8)));
typedef float  f32x4   __attribute__((ext_vector_type(4)));

#define WS_WB_SHORTS 8192   // wb blob starts at short offset 8192 (16 KB)

static __device__ __forceinline__ unsigned short f2bf(float f) {
    union { float f; unsigned u; } v; v.f = f;
    unsigned r = v.u + 0x7FFFu + ((v.u >> 16) & 1u);   // RNE
    return (unsigned short)(r >> 16);
}

// Build one row's two k-step A-fragments from the LDS x-image.
// k=59 -> 1.0 (bias row; wb blob has 0 there so vv is unaffected), k>59 -> 0.
static __device__ __forceinline__ void frags_from_lds(
    const float* __restrict__ xs, int row, int lg, short8* a)
{
    const float* r = xs + row * FF;
    float xv[8];
    #pragma unroll
    for (int j = 0; j < 8; ++j) xv[j] = r[lg * 8 + j];
    #pragma unroll
    for (int j = 0; j < 8; ++j) a[0][j] = (short)f2bf(xv[j]);
    if (lg < 3) {
        #pragma unroll
        for (int j = 0; j < 8; ++j) xv[j] = r[32 + lg * 8 + j];
    } else {
        xv[0] = r[56]; xv[1] = r[57]; xv[2] = r[58]; xv[3] = 1.0f;
        #pragma unroll
        for (int j = 4; j < 8; ++j) xv[j] = 0.0f;
    }
    #pragma unroll
    for (int j = 0; j < 8; ++j) a[1][j] = (short)f2bf(xv[j]);
}

// ---------------------------------------------------------------------------
// Kernel B: build wu blob (blocks 0..15) and wb blob (blocks 16..31).
// frag (s,nt) at ((s*8+nt)*64 + lane)*8 shorts; lane gives d = nt*16+(l&15),
// k0 = s*32+(l>>4)*8 — exactly the MFMA B-fragment each lane needs.
// ---------------------------------------------------------------------------
__global__ __launch_bounds__(64) void ecn_blob(
    const float* __restrict__ w1, const float* __restrict__ b1,
    short* __restrict__ blob)
{
    const int bid = blockIdx.x;
    const int l = threadIdx.x;
    const bool isB = (bid >= 16);
    const int fid = isB ? (bid - 16) : bid;
    const int s = fid >> 3, nt = fid & 7;
    const int lr = l & 15, lg = l >> 4;
    const int d = nt * 16 + lr, k0 = s * 32 + lg * 8;
    short8 pk;
    #pragma unroll
    for (int j = 0; j < 8; ++j) {
        int k = k0 + j;
        float v = 0.0f;
        if (k < FF) {
            float wb_ = w1[(size_t)(FF + k) * D1 + d];
            v = isB ? wb_ : (w1[(size_t)k * D1 + d] - wb_);
        } else if (k == FF && !isB) {
            v = b1[d];                       // bias row only in wu
        }
        pk[j] = (short)f2bf(v);
    }
    *(short8*)&blob[(size_t)(isB ? WS_WB_SHORTS : 0) + ((s * 8 + nt) * 64 + l) * 8] = pk;
}

// ---------------------------------------------------------------------------
// Kernel F: per-graph fused, wave-decoupled. Wave-local x staging + per-wave
// vv (shfl-distributed) + per-nt streaming u-GEMM + BN1 + head MLP + sigmoid.
// ---------------------------------------------------------------------------
__global__ __launch_bounds__(256, 4) void ecn_fused(
    const float* __restrict__ x, const short* __restrict__ blob,
    const float* __restrict__ g1, const float* __restrict__ be1,
    const float* __restrict__ m1, const float* __restrict__ v1,
    const float* __restrict__ w2, const float* __restrict__ b2,
    const float* __restrict__ g2, const float* __restrict__ be2,
    const float* __restrict__ m2, const float* __restrict__ v2,
    const float* __restrict__ w3, const float* __restrict__ b3,
    const float* __restrict__ g3, const float* __restrict__ be3,
    const float* __restrict__ m3, const float* __restrict__ v3,
    float* __restrict__ out)
{
    // XCD-aware bijective swizzle: 1000 = 8 * 125
    const int bid = blockIdx.x;
    const int g = (bid & 7) * 125 + (bid >> 3);
    const int t = threadIdx.x;

    __shared__ __align__(16) float xs[NPG * FF];   // 30208 B, linear f32 image
    __shared__ float Sp[4][D1];      // 2 KB
    __shared__ float x2s[D1];        // 512 B
    __shared__ float rpart[4];
    // total ~33 KB -> 4 blocks/CU

    const int wave = t >> 6, l = t & 63;
    const int lr = l & 15, lg = l >> 4;
    const float* xg = x + (size_t)g * NPG * FF;

    // ---- wave-local staging: wave w stages rows w*32..w*32+31 (472 float4) ----
    {
        const float4* xg4 = (const float4*)xg;
        float4* xs4 = (float4*)xs;
        const int base = wave * 472;
        #pragma unroll
        for (int k = 0; k < 8; ++k) {
            int off = base + k * 64 + l;
            if (k < 7 || l < 24)
                __builtin_amdgcn_global_load_lds(&xg4[off], &xs4[off], 16, 0, 0);
        }
    }

    // ---- av (rows 0..15) direct from global for waves 1..3, concurrent ----
    float avf0[8], avf1[8];
    if (wave != 0) {
        const float* r = xg + lr * FF;
        #pragma unroll
        for (int j = 0; j < 8; ++j) avf0[j] = r[lg * 8 + j];
        if (lg < 3) {
            #pragma unroll
            for (int j = 0; j < 8; ++j) avf1[j] = r[32 + lg * 8 + j];
        } else {
            avf1[0] = r[56]; avf1[1] = r[57]; avf1[2] = r[58]; avf1[3] = 1.0f;
            avf1[4] = avf1[5] = avf1[6] = avf1[7] = 0.0f;
        }
    }

    // per-wave drain of staging + av loads (no block barrier)
    asm volatile("s_waitcnt vmcnt(0)" ::: "memory");
    __builtin_amdgcn_sched_barrier(0);

    // ---- A fragments from own LDS section ----
    const int i0 = wave * 32 + lr, i1 = i0 + 16;
    short8 a0[2], a1[2], av[2];
    frags_from_lds(xs, i0, lg, a0);
    frags_from_lds(xs, i1, lg, a1);
    if (wave == 0) { av[0] = a0[0]; av[1] = a0[1]; }   // wave 0: lr == i0
    else {
        #pragma unroll
        for (int j = 0; j < 8; ++j) {
            av[0][j] = (short)f2bf(avf0[j]);
            av[1][j] = (short)f2bf(avf1[j]);
        }
    }

    const short8* wu8 = (const short8*)blob;
    const short8* wb8 = (const short8*)(blob + WS_WB_SHORTS);

    // ---- per-wave full vv: rows 0..15 x w1b, all 8 nt-tiles (stays in regs) ----
    f32x4 accv[8];
    #pragma unroll
    for (int nt = 0; nt < 8; ++nt) accv[nt] = (f32x4)0.0f;
    #pragma unroll
    for (int s = 0; s < 2; ++s)
        #pragma unroll
        for (int nt = 0; nt < 8; ++nt)
            accv[nt] = __builtin_amdgcn_mfma_f32_16x16x32_bf16(
                av[s], wb8[(s * 8 + nt) * 64 + l], accv[nt], 0, 0, 0);

    // ---- per-nt streaming u-GEMM + fused relu-edge aggregation (shfl-vv) ----
    #pragma unroll
    for (int nt = 0; nt < 8; ++nt) {
        short8 b0 = wu8[nt * 64 + l];
        short8 b1f = wu8[(8 + nt) * 64 + l];
        f32x4 c0 = (f32x4)0.0f, c1 = (f32x4)0.0f;
        c0 = __builtin_amdgcn_mfma_f32_16x16x32_bf16(a0[0], b0,  c0, 0, 0, 0);
        c0 = __builtin_amdgcn_mfma_f32_16x16x32_bf16(a0[1], b1f, c0, 0, 0, 0);
        c1 = __builtin_amdgcn_mfma_f32_16x16x32_bf16(a1[0], b0,  c1, 0, 0, 0);
        c1 = __builtin_amdgcn_mfma_f32_16x16x32_bf16(a1[1], b1f, c1, 0, 0, 0);

        // vv rows 0..3 of col d=nt*16+lr live in lane lr (lg=0), accv[nt][q]
        const float v0  = __shfl(accv[nt][0], lr);
        const float v1_ = __shfl(accv[nt][1], lr);
        const float v2_ = __shfl(accv[nt][2], lr);
        const float v3_ = __shfl(accv[nt][3], lr);
        float s = 0.0f;
        #pragma unroll
        for (int q = 0; q < 4; ++q) {
            float u = c0[q];              // b1 already inside via k=59 row
            s += fmaxf(u + v0, 0.0f) + fmaxf(u + v1_, 0.0f) + fmaxf(u + v2_, 0.0f);
            u = c1[q];
            s += fmaxf(u + v0, 0.0f) + fmaxf(u + v1_, 0.0f) + fmaxf(u + v2_, 0.0f);
        }
        if (wave == 0 && lg == 0) {       // global rows 0,1,2 = c0 q=0..2
            float u0 = c0[0], u1 = c0[1], u2 = c0[2];
            s += fmaxf(u0 + v3_, 0.0f) - fmaxf(u0 + v0,  0.0f);
            s += fmaxf(u1 + v3_, 0.0f) - fmaxf(u1 + v1_, 0.0f);
            s += fmaxf(u2 + v3_, 0.0f) - fmaxf(u2 + v2_, 0.0f);
        }
        s += __shfl_xor(s, 16);
        s += __shfl_xor(s, 32);
        if (lg == 0) Sp[wave][nt * 16 + lr] = s;
    }
    __syncthreads();

    // ---- BN1 (affine commutes with the means) -> x2 in LDS ----
    if (t < D1) {
        float tot = Sp[0][t] + Sp[1][t] + Sp[2][t] + Sp[3][t];
        float sc = g1[t] * rsqrtf(v1[t] + EPSV);
        x2s[t] = sc * (tot * (1.0f / (3 * NPG))) + (be1[t] - m1[t] * sc);
    }
    __syncthreads();

    // ---- head MLP + sigmoid (4 independent FMA chains for ILP) ----
    {
        float h0 = b2[t], h1 = 0.0f, h2 = 0.0f, h3 = 0.0f;
        #pragma unroll 8
        for (int f = 0; f < D1; f += 4) {
            h0 = fmaf(x2s[f],     w2[(size_t)f * D2 + t],       h0);
            h1 = fmaf(x2s[f + 1], w2[(size_t)(f + 1) * D2 + t], h1);
            h2 = fmaf(x2s[f + 2], w2[(size_t)(f + 2) * D2 + t], h2);
            h3 = fmaf(x2s[f + 3], w2[(size_t)(f + 3) * D2 + t], h3);
        }
        float h = (h0 + h1) + (h2 + h3);
        h = fmaxf(h, 0.0f);
        float sc2 = g2[t] * rsqrtf(v2[t] + EPSV);
        h = sc2 * h + (be2[t] - m2[t] * sc2);
        float r = h * w3[t];
        #pragma unroll
        for (int off = 32; off > 0; off >>= 1) r += __shfl_down(r, off);
        if ((t & 63) == 0) rpart[t >> 6] = r;
    }
    __syncthreads();
    if (t == 0) {
        float s = rpart[0] + rpart[1] + rpart[2] + rpart[3] + b3[0];
        s = fmaxf(s, 0.0f);
        float sc3 = g3[0] * rsqrtf(v3[0] + EPSV);
        s = sc3 * s + (be3[0] - m3[0] * sc3);
        out[g] = 1.0f / (1.0f + expf(-s));
    }
}

extern "C" void kernel_launch(void* const* d_in, const int* in_sizes, int n_in,
                              void* d_out, int out_size, void* d_ws, size_t ws_size,
                              hipStream_t stream) {
    const float* x   = (const float*)d_in[0];
    // d_in[1] = pos — unused: the reference's knn degenerates (see NOTE)
    const float* w1  = (const float*)d_in[2];
    const float* b1  = (const float*)d_in[3];
    const float* g1  = (const float*)d_in[4];
    const float* be1 = (const float*)d_in[5];
    const float* m1  = (const float*)d_in[6];
    const float* v1  = (const float*)d_in[7];
    const float* w2  = (const float*)d_in[8];
    const float* b2  = (const float*)d_in[9];
    const float* g2  = (const float*)d_in[10];
    const float* be2 = (const float*)d_in[11];
    const float* m2  = (const float*)d_in[12];
    const float* v2  = (const float*)d_in[13];
    const float* w3  = (const float*)d_in[14];
    const float* b3  = (const float*)d_in[15];
    const float* g3  = (const float*)d_in[16];
    const float* be3 = (const float*)d_in[17];
    const float* m3  = (const float*)d_in[18];
    const float* v3  = (const float*)d_in[19];
    float* outp = (float*)d_out;

    short* blob = (short*)d_ws;

    ecn_blob<<<32, 64, 0, stream>>>(w1, b1, blob);
    ecn_fused<<<NG, 256, 0, stream>>>(x, blob, g1, be1, m1, v1,
                                      w2, b2, g2, be2, m2, v2,
                                      w3, b3, g3, be3, m3, v3, outp);
}

// Round 20
// 21.724 us; speedup vs baseline: 1.0967x; 1.0899x over previous
//
#include <hip/hip_runtime.h>
#include <math.h>

// Problem constants (from setup_inputs)
#define NG    1000   // num_graphs
#define NPG   128    // nodes_per_graph
#define FF    59     // features
#define D1    128    // hidden 1
#define D2    256    // hidden 2
#define EPSV  1e-5f

// NOTE on the neighbor graph: the reference's  d2 + eye(n)*inf  makes every
// OFF-diagonal entry 0*inf = NaN (diag = +inf); top_k(-d2) then selects,
// stably, the 3 lowest indices != i:
//   idx[i] = {0,1,2} for i>=3;  {1,2,3}, {0,2,3}, {0,1,3} for i=0,1,2.
// So v_j = x_j @ w1b is only needed for j in {0,1,2,3}, and
//   sum_edges relu(u_i + v_j) = sum_i S3(i) + sum_{i<3} [relu(u_i+v3) - relu(u_i+v_i)]
// where S3(i) = relu(u_i+v0)+relu(u_i+v1)+relu(u_i+v2),
//       u_i = x_i @ (w1a - w1b) + b1   (b1 folded into wu's k=59 row, x pad=1.0)
//
// Round-20: ONE launch (the 2nd launch boundary ≈ 4 us by R5/R6->R9 vs R13
// ledger). Per-block blob built in LDS from COALESCED w1 reads (w1 is
// [118][128] row-major -> e=t+i*256 is a perfect dword stream, L2-resident)
// with transposed ds_write_b16 fills — unlike R10 (strided per-thread gather)
// and R14 (cross-block coherence), the two failed 1-launch attempts.
// x fragments direct-global (R13-proven), L2-hot via the XCD swizzle (R17).
// B-fragments become conflict-free ds_read_b128 (stride-16 canonical).
// Body otherwise = R19 (wave-decoupled vv via shfl, per-nt streaming u-GEMM,
// BN1 + fp32-w2 head). LDS ~35 KB -> 4 blocks/CU. Zero ws.

typedef short  short8  __attribute__((ext_vector_type(8)));
typedef float  f32x4   __attribute__((ext_vector_type(4)));
typedef unsigned short ushort4_t __attribute__((ext_vector_type(4)));

static __device__ __forceinline__ unsigned short f2bf(float f) {
    union { float f; unsigned u; } v; v.f = f;
    unsigned r = v.u + 0x7FFFu + ((v.u >> 16) & 1u);   // RNE
    return (unsigned short)(r >> 16);
}

// Build one row's two k-step MFMA A-fragments from a GLOBAL row pointer.
// k=59 -> 1.0 (bias row; wb has 0 there so vv is unaffected), k>59 -> 0.
static __device__ __forceinline__ void load_frags_g(
    const float* __restrict__ row, int lg, short8* a)
{
    float xv[8];
    const float* p = row + lg * 8;
    #pragma unroll
    for (int j = 0; j < 8; ++j) xv[j] = p[j];
    #pragma unroll
    for (int j = 0; j < 8; ++j) a[0][j] = (short)f2bf(xv[j]);
    if (lg < 3) {
        const float* q = row + 32 + lg * 8;
        #pragma unroll
        for (int j = 0; j < 8; ++j) xv[j] = q[j];
    } else {
        xv[0] = row[56]; xv[1] = row[57]; xv[2] = row[58]; xv[3] = 1.0f;
        #pragma unroll
        for (int j = 4; j < 8; ++j) xv[j] = 0.0f;
    }
    #pragma unroll
    for (int j = 0; j < 8; ++j) a[1][j] = (short)f2bf(xv[j]);
}

// ---------------------------------------------------------------------------
// ONE kernel: per-block LDS blob build + per-graph fused EdgeConv+BN1+head.
// blob layout (shorts): frag (s,nt) at ((s*8+nt)*64 + lane)*8; lane gives
// d = nt*16+(lane&15), k0 = s*32+(lane>>4)*8. wu at [0,8192), wb at [8192,16384).
// ---------------------------------------------------------------------------
__global__ __launch_bounds__(256, 4) void ecn_one(
    const float* __restrict__ x,
    const float* __restrict__ w1, const float* __restrict__ b1,
    const float* __restrict__ g1, const float* __restrict__ be1,
    const float* __restrict__ m1, const float* __restrict__ v1,
    const float* __restrict__ w2, const float* __restrict__ b2,
    const float* __restrict__ g2, const float* __restrict__ be2,
    const float* __restrict__ m2, const float* __restrict__ v2,
    const float* __restrict__ w3, const float* __restrict__ b3,
    const float* __restrict__ g3, const float* __restrict__ be3,
    const float* __restrict__ m3, const float* __restrict__ v3,
    float* __restrict__ out)
{
    // XCD-aware bijective swizzle: 1000 = 8 * 125
    const int bid = blockIdx.x;
    const int g = (bid & 7) * 125 + (bid >> 3);
    const int t = threadIdx.x;

    __shared__ __align__(16) short lb[16384];   // 32 KB: wu + wb fragment blobs
    __shared__ float Sp[4][D1];      // 2 KB
    __shared__ float x2s[D1];        // 512 B
    __shared__ float rpart[4];
    // total ~35 KB -> 4 blocks/CU

    const float* xg = x + (size_t)g * NPG * FF;
    const int wave = t >> 6, l = t & 63;
    const int lr = l & 15, lg = l >> 4;
    const int i0 = wave * 32 + lr, i1 = i0 + 16;

    // ---- x fragments direct from global (issued early; L2-hot via swizzle) ----
    short8 a0[2], a1[2], av[2];
    load_frags_g(xg + i0 * FF, lg, a0);
    load_frags_g(xg + i1 * FF, lg, a1);
    if (wave == 0) { av[0] = a0[0]; av[1] = a0[1]; }   // wave 0: lr == i0
    else           load_frags_g(xg + lr * FF, lg, av);

    // ---- blob fill: coalesced w1 dword streams -> transposed LDS writes ----
    // e = k*128 + d (w1 is [118][128] row-major); k<59: wu = w1a-w1b, wb = w1b
    #pragma unroll 5
    for (int i = 0; i < 30; ++i) {
        int e = t + i * 256;
        if (i < 29 || e < FF * D1) {
            int k = e >> 7, d = e & 127;
            float wa  = w1[e];
            float wbv = w1[e + FF * D1];
            int fb = (((k >> 5) * 8 + (d >> 4)) * 64 + ((k >> 3) & 3) * 16 + (d & 15)) * 8 + (k & 7);
            lb[fb]        = (short)f2bf(wa - wbv);
            lb[8192 + fb] = (short)f2bf(wbv);
        }
    }
    // pad rows k=59..63 (s=1, lg=3, j=3..7) — disjoint from the fill (j<=2 there)
    if (t < 128) {
        int fb = ((8 + (t >> 4)) * 64 + 48 + (t & 15)) * 8;
        lb[fb + 3] = (short)f2bf(b1[t]);            // wu bias row k=59
        *(ushort4_t*)&lb[fb + 4] = (ushort4_t)0;    // wu k=60..63
        lb[8192 + fb + 3] = 0;                      // wb k=59
        *(ushort4_t*)&lb[8192 + fb + 4] = (ushort4_t)0;
    }
    __syncthreads();                                // blob complete

    const short8* wu8 = (const short8*)lb;
    const short8* wb8 = (const short8*)(lb + 8192);

    // ---- per-wave full vv: rows 0..15 x w1b, all 8 nt-tiles (in regs) ----
    f32x4 accv[8];
    #pragma unroll
    for (int nt = 0; nt < 8; ++nt) accv[nt] = (f32x4)0.0f;
    #pragma unroll
    for (int s = 0; s < 2; ++s)
        #pragma unroll
        for (int nt = 0; nt < 8; ++nt)
            accv[nt] = __builtin_amdgcn_mfma_f32_16x16x32_bf16(
                av[s], wb8[(s * 8 + nt) * 64 + l], accv[nt], 0, 0, 0);

    // ---- per-nt streaming u-GEMM + fused relu-edge aggregation (shfl-vv) ----
    #pragma unroll
    for (int nt = 0; nt < 8; ++nt) {
        short8 b0  = wu8[nt * 64 + l];
        short8 b1f = wu8[(8 + nt) * 64 + l];
        f32x4 c0 = (f32x4)0.0f, c1 = (f32x4)0.0f;
        c0 = __builtin_amdgcn_mfma_f32_16x16x32_bf16(a0[0], b0,  c0, 0, 0, 0);
        c0 = __builtin_amdgcn_mfma_f32_16x16x32_bf16(a0[1], b1f, c0, 0, 0, 0);
        c1 = __builtin_amdgcn_mfma_f32_16x16x32_bf16(a1[0], b0,  c1, 0, 0, 0);
        c1 = __builtin_amdgcn_mfma_f32_16x16x32_bf16(a1[1], b1f, c1, 0, 0, 0);

        // vv rows 0..3 of col d=nt*16+lr live in lane lr (lg=0), accv[nt][q]
        const float v0  = __shfl(accv[nt][0], lr);
        const float v1_ = __shfl(accv[nt][1], lr);
        const float v2_ = __shfl(accv[nt][2], lr);
        const float v3_ = __shfl(accv[nt][3], lr);
        float s = 0.0f;
        #pragma unroll
        for (int q = 0; q < 4; ++q) {
            float u = c0[q];              // b1 already inside via k=59 row
            s += fmaxf(u + v0, 0.0f) + fmaxf(u + v1_, 0.0f) + fmaxf(u + v2_, 0.0f);
            u = c1[q];
            s += fmaxf(u + v0, 0.0f) + fmaxf(u + v1_, 0.0f) + fmaxf(u + v2_, 0.0f);
        }
        if (wave == 0 && lg == 0) {       // global rows 0,1,2 = c0 q=0..2
            float u0 = c0[0], u1 = c0[1], u2 = c0[2];
            s += fmaxf(u0 + v3_, 0.0f) - fmaxf(u0 + v0,  0.0f);
            s += fmaxf(u1 + v3_, 0.0f) - fmaxf(u1 + v1_, 0.0f);
            s += fmaxf(u2 + v3_, 0.0f) - fmaxf(u2 + v2_, 0.0f);
        }
        s += __shfl_xor(s, 16);
        s += __shfl_xor(s, 32);
        if (lg == 0) Sp[wave][nt * 16 + lr] = s;
    }
    __syncthreads();

    // ---- BN1 (affine commutes with the means) -> x2 in LDS ----
    if (t < D1) {
        float tot = Sp[0][t] + Sp[1][t] + Sp[2][t] + Sp[3][t];
        float sc = g1[t] * rsqrtf(v1[t] + EPSV);
        x2s[t] = sc * (tot * (1.0f / (3 * NPG))) + (be1[t] - m1[t] * sc);
    }
    __syncthreads();

    // ---- head MLP + sigmoid (4 independent FMA chains for ILP) ----
    {
        float h0 = b2[t], h1 = 0.0f, h2 = 0.0f, h3 = 0.0f;
        #pragma unroll 8
        for (int f = 0; f < D1; f += 4) {
            h0 = fmaf(x2s[f],     w2[(size_t)f * D2 + t],       h0);
            h1 = fmaf(x2s[f + 1], w2[(size_t)(f + 1) * D2 + t], h1);
            h2 = fmaf(x2s[f + 2], w2[(size_t)(f + 2) * D2 + t], h2);
            h3 = fmaf(x2s[f + 3], w2[(size_t)(f + 3) * D2 + t], h3);
        }
        float h = (h0 + h1) + (h2 + h3);
        h = fmaxf(h, 0.0f);
        float sc2 = g2[t] * rsqrtf(v2[t] + EPSV);
        h = sc2 * h + (be2[t] - m2[t] * sc2);
        float r = h * w3[t];
        #pragma unroll
        for (int off = 32; off > 0; off >>= 1) r += __shfl_down(r, off);
        if ((t & 63) == 0) rpart[t >> 6] = r;
    }
    __syncthreads();
    if (t == 0) {
        float s = rpart[0] + rpart[1] + rpart[2] + rpart[3] + b3[0];
        s = fmaxf(s, 0.0f);
        float sc3 = g3[0] * rsqrtf(v3[0] + EPSV);
        s = sc3 * s + (be3[0] - m3[0] * sc3);
        out[g] = 1.0f / (1.0f + expf(-s));
    }
}

extern "C" void kernel_launch(void* const* d_in, const int* in_sizes, int n_in,
                              void* d_out, int out_size, void* d_ws, size_t ws_size,
                              hipStream_t stream) {
    const float* x   = (const float*)d_in[0];
    // d_in[1] = pos — unused: the reference's knn degenerates (see NOTE)
    const float* w1  = (const float*)d_in[2];
    const float* b1  = (const float*)d_in[3];
    const float* g1  = (const float*)d_in[4];
    const float* be1 = (const float*)d_in[5];
    const float* m1  = (const float*)d_in[6];
    const float* v1  = (const float*)d_in[7];
    const float* w2  = (const float*)d_in[8];
    const float* b2  = (const float*)d_in[9];
    const float* g2  = (const float*)d_in[10];
    const float* be2 = (const float*)d_in[11];
    const float* m2  = (const float*)d_in[12];
    const float* v2  = (const float*)d_in[13];
    const float* w3  = (const float*)d_in[14];
    const float* b3  = (const float*)d_in[15];
    const float* g3  = (const float*)d_in[16];
    const float* be3 = (const float*)d_in[17];
    const float* m3  = (const float*)d_in[18];
    const float* v3  = (const float*)d_in[19];
    float* outp = (float*)d_out;

    ecn_one<<<NG, 256, 0, stream>>>(x, w1, b1, g1, be1, m1, v1,
                                    w2, b2, g2, be2, m2, v2,
                                    w3, b3, g3, be3, m3, v3, outp);
}

// Round 21
// 19.907 us; speedup vs baseline: 1.1968x; 1.0912x over previous
//
#include <hip/hip_runtime.h>
#include <math.h>

// Problem constants (from setup_inputs)
#define NG    1000   // num_graphs
#define NPG   128    // nodes_per_graph
#define FF    59     // features
#define D1    128    // hidden 1
#define D2    256    // hidden 2
#define EPSV  1e-5f

// NOTE on the neighbor graph: the reference's  d2 + eye(n)*inf  makes every
// OFF-diagonal entry 0*inf = NaN (diag = +inf); top_k(-d2) then selects,
// stably, the 3 lowest indices != i:
//   idx[i] = {0,1,2} for i>=3;  {1,2,3}, {0,2,3}, {0,1,3} for i=0,1,2.
// So v_j = x_j @ w1b is only needed for j in {0,1,2,3}, and
//   sum_edges relu(u_i + v_j) = sum_i S3(i) + sum_{i<3} [relu(u_i+v3) - relu(u_i+v_i)]
// where S3(i) = relu(u_i+v0)+relu(u_i+v1)+relu(u_i+v2),
//       u_i = x_i @ (w1a - w1b) + b1   (b1 folded into wu's k=59 row, x pad=1.0)
//
// Round-21: R20 (best, 21.72, 1 launch) + 2 graphs per 512-thread block:
// waves 0-3 -> graph A, waves 4-7 -> graph B. Blob built ONCE per 2 graphs
// (fleet w1 traffic halved), head w2 read once per 2 graphs (halved), grid
// 500 with general bijective XCD swizzle (500 = 8*62 + 4, m204 formula).
// Per-wave work and total wave count unchanged (500*8 = 4000 waves).

typedef short  short8  __attribute__((ext_vector_type(8)));
typedef float  f32x4   __attribute__((ext_vector_type(4)));
typedef unsigned short ushort4_t __attribute__((ext_vector_type(4)));

static __device__ __forceinline__ unsigned short f2bf(float f) {
    union { float f; unsigned u; } v; v.f = f;
    unsigned r = v.u + 0x7FFFu + ((v.u >> 16) & 1u);   // RNE
    return (unsigned short)(r >> 16);
}

// Build one row's two k-step MFMA A-fragments from a GLOBAL row pointer.
// k=59 -> 1.0 (bias row; wb has 0 there so vv is unaffected), k>59 -> 0.
static __device__ __forceinline__ void load_frags_g(
    const float* __restrict__ row, int lg, short8* a)
{
    float xv[8];
    const float* p = row + lg * 8;
    #pragma unroll
    for (int j = 0; j < 8; ++j) xv[j] = p[j];
    #pragma unroll
    for (int j = 0; j < 8; ++j) a[0][j] = (short)f2bf(xv[j]);
    if (lg < 3) {
        const float* q = row + 32 + lg * 8;
        #pragma unroll
        for (int j = 0; j < 8; ++j) xv[j] = q[j];
    } else {
        xv[0] = row[56]; xv[1] = row[57]; xv[2] = row[58]; xv[3] = 1.0f;
        #pragma unroll
        for (int j = 4; j < 8; ++j) xv[j] = 0.0f;
    }
    #pragma unroll
    for (int j = 0; j < 8; ++j) a[1][j] = (short)f2bf(xv[j]);
}

// ---------------------------------------------------------------------------
// ONE kernel, 512 threads, 2 graphs per block.
// blob layout (shorts): frag (s,nt) at ((s*8+nt)*64 + lane)*8; lane gives
// d = nt*16+(lane&15), k0 = s*32+(lane>>4)*8. wu at [0,8192), wb at [8192,16384).
// ---------------------------------------------------------------------------
__global__ __launch_bounds__(512, 4) void ecn_one(
    const float* __restrict__ x,
    const float* __restrict__ w1, const float* __restrict__ b1,
    const float* __restrict__ g1, const float* __restrict__ be1,
    const float* __restrict__ m1, const float* __restrict__ v1,
    const float* __restrict__ w2, const float* __restrict__ b2,
    const float* __restrict__ g2, const float* __restrict__ be2,
    const float* __restrict__ m2, const float* __restrict__ v2,
    const float* __restrict__ w3, const float* __restrict__ b3,
    const float* __restrict__ g3, const float* __restrict__ be3,
    const float* __restrict__ m3, const float* __restrict__ v3,
    float* __restrict__ out)
{
    // bijective XCD swizzle for nwg=500: q=62, r=4 (m204 formula)
    const int bid = blockIdx.x;
    const int xcd = bid & 7, o = bid >> 3;
    const int gp = (xcd < 4 ? xcd * 63 : 252 + (xcd - 4) * 62) + o;  // graph pair
    const int t = threadIdx.x;

    __shared__ __align__(16) short lb[16384];   // 32 KB: wu + wb fragment blobs
    __shared__ float Sp[8][D1];      // 4 KB
    __shared__ float x2s[2][D1];     // 1 KB
    __shared__ float rpart[2][4];
    // total ~37.3 KB

    const int wave = t >> 6, l = t & 63;
    const int gi = wave >> 2, w4 = wave & 3;
    const int lr = l & 15, lg = l >> 4;
    const int g = gp * 2 + gi;
    const float* xg = x + (size_t)g * NPG * FF;
    const int i0 = w4 * 32 + lr, i1 = i0 + 16;

    // ---- x fragments direct from global (issued early; L2-hot via swizzle) ----
    short8 a0[2], a1[2], av[2];
    load_frags_g(xg + i0 * FF, lg, a0);
    load_frags_g(xg + i1 * FF, lg, a1);
    if (w4 == 0) { av[0] = a0[0]; av[1] = a0[1]; }   // w4==0: lr == i0
    else         load_frags_g(xg + lr * FF, lg, av);

    // ---- blob fill (once per 2 graphs): coalesced w1 streams -> LDS ----
    // e = k*128 + d (w1 is [118][128] row-major); k<59: wu = w1a-w1b, wb = w1b
    #pragma unroll 5
    for (int i = 0; i < 15; ++i) {
        int e = t + i * 512;
        if (i < 14 || e < FF * D1) {
            int k = e >> 7, d = e & 127;
            float wa  = w1[e];
            float wbv = w1[e + FF * D1];
            int fb = (((k >> 5) * 8 + (d >> 4)) * 64 + ((k >> 3) & 3) * 16 + (d & 15)) * 8 + (k & 7);
            lb[fb]        = (short)f2bf(wa - wbv);
            lb[8192 + fb] = (short)f2bf(wbv);
        }
    }
    // pad rows k=59..63 (s=1, lg=3, j=3..7) — disjoint from the fill (j<=2 there)
    if (t < 128) {
        int fb = ((8 + (t >> 4)) * 64 + 48 + (t & 15)) * 8;
        lb[fb + 3] = (short)f2bf(b1[t]);            // wu bias row k=59
        *(ushort4_t*)&lb[fb + 4] = (ushort4_t)0;    // wu k=60..63
        lb[8192 + fb + 3] = 0;                      // wb k=59
        *(ushort4_t*)&lb[8192 + fb + 4] = (ushort4_t)0;
    }
    __syncthreads();                                // blob complete

    const short8* wu8 = (const short8*)lb;
    const short8* wb8 = (const short8*)(lb + 8192);

    // ---- per-wave full vv: rows 0..15 x w1b, all 8 nt-tiles (in regs) ----
    f32x4 accv[8];
    #pragma unroll
    for (int nt = 0; nt < 8; ++nt) accv[nt] = (f32x4)0.0f;
    #pragma unroll
    for (int s = 0; s < 2; ++s)
        #pragma unroll
        for (int nt = 0; nt < 8; ++nt)
            accv[nt] = __builtin_amdgcn_mfma_f32_16x16x32_bf16(
                av[s], wb8[(s * 8 + nt) * 64 + l], accv[nt], 0, 0, 0);

    // ---- per-nt streaming u-GEMM + fused relu-edge aggregation (shfl-vv) ----
    #pragma unroll
    for (int nt = 0; nt < 8; ++nt) {
        short8 b0  = wu8[nt * 64 + l];
        short8 b1f = wu8[(8 + nt) * 64 + l];
        f32x4 c0 = (f32x4)0.0f, c1 = (f32x4)0.0f;
        c0 = __builtin_amdgcn_mfma_f32_16x16x32_bf16(a0[0], b0,  c0, 0, 0, 0);
        c0 = __builtin_amdgcn_mfma_f32_16x16x32_bf16(a0[1], b1f, c0, 0, 0, 0);
        c1 = __builtin_amdgcn_mfma_f32_16x16x32_bf16(a1[0], b0,  c1, 0, 0, 0);
        c1 = __builtin_amdgcn_mfma_f32_16x16x32_bf16(a1[1], b1f, c1, 0, 0, 0);

        // vv rows 0..3 of col d=nt*16+lr live in lane lr (lg=0), accv[nt][q]
        const float v0  = __shfl(accv[nt][0], lr);
        const float v1_ = __shfl(accv[nt][1], lr);
        const float v2_ = __shfl(accv[nt][2], lr);
        const float v3_ = __shfl(accv[nt][3], lr);
        float s = 0.0f;
        #pragma unroll
        for (int q = 0; q < 4; ++q) {
            float u = c0[q];              // b1 already inside via k=59 row
            s += fmaxf(u + v0, 0.0f) + fmaxf(u + v1_, 0.0f) + fmaxf(u + v2_, 0.0f);
            u = c1[q];
            s += fmaxf(u + v0, 0.0f) + fmaxf(u + v1_, 0.0f) + fmaxf(u + v2_, 0.0f);
        }
        if (w4 == 0 && lg == 0) {         // global rows 0,1,2 = c0 q=0..2
            float u0 = c0[0], u1 = c0[1], u2 = c0[2];
            s += fmaxf(u0 + v3_, 0.0f) - fmaxf(u0 + v0,  0.0f);
            s += fmaxf(u1 + v3_, 0.0f) - fmaxf(u1 + v1_, 0.0f);
            s += fmaxf(u2 + v3_, 0.0f) - fmaxf(u2 + v2_, 0.0f);
        }
        s += __shfl_xor(s, 16);
        s += __shfl_xor(s, 32);
        if (lg == 0) Sp[wave][nt * 16 + lr] = s;
    }
    __syncthreads();

    // ---- BN1 (affine commutes with the means) -> x2 in LDS (per graph) ----
    {
        const int lt = t & 255, gg = t >> 8;
        if (lt < D1) {
            float tot = Sp[gg * 4 + 0][lt] + Sp[gg * 4 + 1][lt]
                      + Sp[gg * 4 + 2][lt] + Sp[gg * 4 + 3][lt];
            float sc = g1[lt] * rsqrtf(v1[lt] + EPSV);
            x2s[gg][lt] = sc * (tot * (1.0f / (3 * NPG))) + (be1[lt] - m1[lt] * sc);
        }
    }
    __syncthreads();

    // ---- head MLP + sigmoid: both graphs, w2 columns read once (broadcast) ----
    {
        const int lt = t & 255, gg = t >> 8;
        float h0 = b2[lt], h1 = 0.0f, h2 = 0.0f, h3 = 0.0f;
        #pragma unroll 8
        for (int f = 0; f < D1; f += 4) {
            h0 = fmaf(x2s[gg][f],     w2[(size_t)f * D2 + lt],       h0);
            h1 = fmaf(x2s[gg][f + 1], w2[(size_t)(f + 1) * D2 + lt], h1);
            h2 = fmaf(x2s[gg][f + 2], w2[(size_t)(f + 2) * D2 + lt], h2);
            h3 = fmaf(x2s[gg][f + 3], w2[(size_t)(f + 3) * D2 + lt], h3);
        }
        float h = (h0 + h1) + (h2 + h3);
        h = fmaxf(h, 0.0f);
        float sc2 = g2[lt] * rsqrtf(v2[lt] + EPSV);
        h = sc2 * h + (be2[lt] - m2[lt] * sc2);
        float r = h * w3[lt];
        #pragma unroll
        for (int off = 32; off > 0; off >>= 1) r += __shfl_down(r, off);
        if ((t & 63) == 0) rpart[gg][(lt) >> 6] = r;
    }
    __syncthreads();
    if ((t & 255) == 0) {
        const int gg = t >> 8;
        float s = rpart[gg][0] + rpart[gg][1] + rpart[gg][2] + rpart[gg][3] + b3[0];
        s = fmaxf(s, 0.0f);
        float sc3 = g3[0] * rsqrtf(v3[0] + EPSV);
        s = sc3 * s + (be3[0] - m3[0] * sc3);
        out[gp * 2 + gg] = 1.0f / (1.0f + expf(-s));
    }
}

extern "C" void kernel_launch(void* const* d_in, const int* in_sizes, int n_in,
                              void* d_out, int out_size, void* d_ws, size_t ws_size,
                              hipStream_t stream) {
    const float* x   = (const float*)d_in[0];
    // d_in[1] = pos — unused: the reference's knn degenerates (see NOTE)
    const float* w1  = (const float*)d_in[2];
    const float* b1  = (const float*)d_in[3];
    const float* g1  = (const float*)d_in[4];
    const float* be1 = (const float*)d_in[5];
    const float* m1  = (const float*)d_in[6];
    const float* v1  = (const float*)d_in[7];
    const float* w2  = (const float*)d_in[8];
    const float* b2  = (const float*)d_in[9];
    const float* g2  = (const float*)d_in[10];
    const float* be2 = (const float*)d_in[11];
    const float* m2  = (const float*)d_in[12];
    const float* v2  = (const float*)d_in[13];
    const float* w3  = (const float*)d_in[14];
    const float* b3  = (const float*)d_in[15];
    const float* g3  = (const float*)d_in[16];
    const float* be3 = (const float*)d_in[17];
    const float* m3  = (const float*)d_in[18];
    const float* v3  = (const float*)d_in[19];
    float* outp = (float*)d_out;

    ecn_one<<<NG / 2, 512, 0, stream>>>(x, w1, b1, g1, be1, m1, v1,
                                        w2, b2, g2, be2, m2, v2,
                                        w3, b3, g3, be3, m3, v3, outp);
}